// Round 9
// baseline (544.309 us; speedup 1.0000x reference)
//
#include <hip/hip_runtime.h>

typedef unsigned short u16;
typedef unsigned int u32;
typedef short v8s __attribute__((ext_vector_type(8)));
typedef short v4s __attribute__((ext_vector_type(4)));
typedef float v4f __attribute__((ext_vector_type(4)));

__device__ __forceinline__ float b2f(u16 v) {
    return __uint_as_float(((u32)v) << 16);
}
__device__ __forceinline__ u16 f2b(float f) {
    u32 u = __float_as_uint(f);
    return (u16)((u + 0x7FFFu + ((u >> 16) & 1u)) >> 16);
}
// async global->LDS, 16B per lane; LDS dest must be wave-uniform base + lane*16
__device__ __forceinline__ void glds16(const u16* g, u16* l) {
    __builtin_amdgcn_global_load_lds((__attribute__((address_space(1))) void*)g,
                                     (__attribute__((address_space(3))) void*)l, 16, 0, 0);
}

// ---------------- dtype detect: bf16 vs f32 reinterpretation ----------------
__global__ void detect_k(const void* x, int* flag) {
    __shared__ int cnt;
    if (threadIdx.x == 0) cnt = 0;
    __syncthreads();
    const u16* p = (const u16*)x;
    int bad = 0;
    for (int i = threadIdx.x; i < 4096; i += 256) {
        int e = (p[i] >> 7) & 0xFF;
        if (e != 0 && (e < 100 || e > 140)) bad++;
    }
    atomicAdd(&cnt, bad);
    __syncthreads();
    if (threadIdx.x == 0) *flag = (cnt > 256) ? 1 : 0;
}

// ---------------- convert to bf16 (grid-stride) ----------------
__global__ void cvt_k(const void* __restrict__ src, u16* __restrict__ dst, int n,
                      const int* __restrict__ flag) {
    const int isf32 = *flag;
    for (int i = blockIdx.x * 256 + threadIdx.x; i < n; i += gridDim.x * 256)
        dst[i] = isf32 ? f2b(((const float*)src)[i]) : ((const u16*)src)[i];
}

// ---------------- fused small-tensor convert (biases + ln params) ----------------
struct P8 { const void* p[8]; };
__global__ void cvt_small_k(P8 src, u16* __restrict__ bb, const int* __restrict__ flag) {
    const int isf32 = *flag;
    const int len[8] = {3072, 1024, 4096, 1024, 1024, 1024, 1024, 1024};
    const int doff[8] = {0, 4096, 8192, 12288, 16384, 17408, 18432, 19456};
    int gi = blockIdx.x * 256 + threadIdx.x;
    int seg = 0, off = gi;
    while (seg < 7 && off >= len[seg]) { off -= len[seg]; seg++; }
    if (off < len[seg]) {
        const void* s = src.p[seg];
        bb[doff[seg] + off] = isf32 ? f2b(((const float*)s)[off]) : ((const u16*)s)[off];
    }
}

// ---------------- transpose+convert: in[R][C] -> out[C][R] bf16 ----------------
__global__ void transpose_k(const void* __restrict__ in, u16* __restrict__ out, int R, int C,
                            const int* __restrict__ flag) {
    __shared__ u16 t[32][33];
    const int isf32 = *flag;
    const int c0 = blockIdx.x * 32, r0 = blockIdx.y * 32;
    for (int i = threadIdx.y; i < 32; i += 8) {
        size_t idx = (size_t)(r0 + i) * C + c0 + threadIdx.x;
        t[i][threadIdx.x] = isf32 ? f2b(((const float*)in)[idx]) : ((const u16*)in)[idx];
    }
    __syncthreads();
    for (int i = threadIdx.y; i < 32; i += 8)
        out[(size_t)(c0 + i) * R + r0 + threadIdx.x] = t[threadIdx.x][i];
}

// ---------------- layernorm: one wave per 1024-elem row (bf16 in ws) ----------------
__global__ __launch_bounds__(256) void layernorm_k(const u16* __restrict__ x,
                                                   const u16* __restrict__ g,
                                                   const u16* __restrict__ bta,
                                                   u16* __restrict__ out) {
    const int wid = threadIdx.x >> 6, lane = threadIdx.x & 63;
    const size_t row = (size_t)blockIdx.x * 4 + wid;
    const u16* xr = x + row * 1024 + lane * 16;
    u16 v[16];
    *(uint4*)&v[0] = *(const uint4*)xr;
    *(uint4*)&v[8] = *(const uint4*)(xr + 8);
    float f[16], s = 0.f, sq = 0.f;
#pragma unroll
    for (int i = 0; i < 16; i++) { f[i] = b2f(v[i]); s += f[i]; sq += f[i] * f[i]; }
#pragma unroll
    for (int d = 1; d < 64; d <<= 1) { s += __shfl_xor(s, d, 64); sq += __shfl_xor(sq, d, 64); }
    const float mean = s * (1.f / 1024.f);
    const float var = sq * (1.f / 1024.f) - mean * mean;
    const float rstd = rsqrtf(var + 1e-5f);
    u16 gv[16], bv[16];
    *(uint4*)&gv[0] = *(const uint4*)(g + lane * 16);
    *(uint4*)&gv[8] = *(const uint4*)(g + lane * 16 + 8);
    *(uint4*)&bv[0] = *(const uint4*)(bta + lane * 16);
    *(uint4*)&bv[8] = *(const uint4*)(bta + lane * 16 + 8);
    u16 ov[16];
#pragma unroll
    for (int i = 0; i < 16; i++) ov[i] = f2b((f[i] - mean) * rstd * b2f(gv[i]) + b2f(bv[i]));
    u16* orow = out + row * 1024 + lane * 16;
    *(uint4*)orow = *(uint4*)&ov[0];
    *(uint4*)(orow + 8) = *(uint4*)&ov[8];
}

// ---------------- generic GEMM (m97 structure): C = A @ Bt^T + bias (+gelu) (+res) ----------------
__global__ __launch_bounds__(256) void gemm_bt_k(const u16* __restrict__ A,
                                                 const u16* __restrict__ Bt,
                                                 const u16* __restrict__ bias,
                                                 const u16* __restrict__ res,
                                                 void* __restrict__ C,
                                                 int M, int N, int K, int do_gelu,
                                                 const int* __restrict__ outf32) {
    __shared__ __align__(16) u16 As[128 * 32];
    __shared__ __align__(16) u16 Bs[128 * 32];
    const int tid = threadIdx.x;
    const int wid = tid >> 6, lane = tid & 63;
    const int lg = lane >> 4, lm = lane & 15;
    const int wr = wid >> 1, wc = wid & 1;
    const int m0 = blockIdx.y * 128, n0 = blockIdx.x * 128;

    const v4f vzero = {0.f, 0.f, 0.f, 0.f};
    v4f acc[4][4];
#pragma unroll
    for (int i = 0; i < 4; i++)
#pragma unroll
        for (int j = 0; j < 4; j++) acc[i][j] = vzero;

    const int srow = tid >> 2;           // 0..63
    const int scol = (tid & 3) * 8;      // 0,8,16,24
    const u16* Ag = A + (size_t)(m0 + srow) * K + scol;
    const u16* Bg = Bt + (size_t)(n0 + srow) * K + scol;
    u16* Asl = &As[tid * 8];             // wave-uniform base + lane*16B
    u16* Bsl = &Bs[tid * 8];
    for (int k0 = 0; k0 < K; k0 += 32) {
        __syncthreads();
        glds16(Ag + k0, Asl);
        glds16(Ag + (size_t)64 * K + k0, Asl + 2048);
        glds16(Bg + k0, Bsl);
        glds16(Bg + (size_t)64 * K + k0, Bsl + 2048);
        __syncthreads();
        v8s af[4], bf[4];
#pragma unroll
        for (int i = 0; i < 4; i++) af[i] = *(const v8s*)&As[(wr * 64 + i * 16 + lm) * 32 + lg * 8];
#pragma unroll
        for (int j = 0; j < 4; j++) bf[j] = *(const v8s*)&Bs[(wc * 64 + j * 16 + lm) * 32 + lg * 8];
#pragma unroll
        for (int i = 0; i < 4; i++)
#pragma unroll
            for (int j = 0; j < 4; j++)
                acc[i][j] = __builtin_amdgcn_mfma_f32_16x16x32_bf16(af[i], bf[j], acc[i][j], 0, 0, 0);
    }

    const int of32 = outf32 ? *outf32 : 0;
#pragma unroll
    for (int i = 0; i < 4; i++) {
#pragma unroll
        for (int r = 0; r < 4; r++) {
            const int row = m0 + wr * 64 + i * 16 + lg * 4 + r;
            const size_t rb = (size_t)row * N;
#pragma unroll
            for (int j = 0; j < 4; j++) {
                const int col = n0 + wc * 64 + j * 16 + lm;
                float v = acc[i][j][r] + b2f(bias[col]);
                if (do_gelu) v = 0.5f * v * (1.0f + erff(v * 0.70710678118f));
                if (res) v += b2f(res[rb + col]);
                if (of32) ((float*)C)[rb + col] = v;
                else ((u16*)C)[rb + col] = f2b(v);
            }
        }
    }
}

// ---------------- QKV GEMM (m97 staging): head-major Q (pre-scaled) / K + permuted V^T ----------------
__global__ __launch_bounds__(256) void gemm_qkv_k(const u16* __restrict__ A,
                                                  const u16* __restrict__ Bt,
                                                  const u16* __restrict__ bias,
                                                  u16* __restrict__ Qh,
                                                  u16* __restrict__ Kh,
                                                  u16* __restrict__ Vth) {
    __shared__ __align__(16) u16 As[128 * 32];
    __shared__ __align__(16) u16 Bs[128 * 32];
    const int tid = threadIdx.x;
    const int wid = tid >> 6, lane = tid & 63;
    const int lg = lane >> 4, lm = lane & 15;
    const int wr = wid >> 1, wc = wid & 1;
    const int m0 = blockIdx.y * 128, n0 = blockIdx.x * 128;
    const int K = 1024;

    const v4f vzero = {0.f, 0.f, 0.f, 0.f};
    v4f acc[4][4];
#pragma unroll
    for (int i = 0; i < 4; i++)
#pragma unroll
        for (int j = 0; j < 4; j++) acc[i][j] = vzero;

    const int srow = tid >> 2;
    const int scol = (tid & 3) * 8;
    const u16* Ag = A + (size_t)(m0 + srow) * K + scol;
    const u16* Bg = Bt + (size_t)(n0 + srow) * K + scol;
    u16* Asl = &As[tid * 8];
    u16* Bsl = &Bs[tid * 8];
    for (int k0 = 0; k0 < K; k0 += 32) {
        __syncthreads();
        glds16(Ag + k0, Asl);
        glds16(Ag + (size_t)64 * K + k0, Asl + 2048);
        glds16(Bg + k0, Bsl);
        glds16(Bg + (size_t)64 * K + k0, Bsl + 2048);
        __syncthreads();
        v8s af[4], bf[4];
#pragma unroll
        for (int i = 0; i < 4; i++) af[i] = *(const v8s*)&As[(wr * 64 + i * 16 + lm) * 32 + lg * 8];
#pragma unroll
        for (int j = 0; j < 4; j++) bf[j] = *(const v8s*)&Bs[(wc * 64 + j * 16 + lm) * 32 + lg * 8];
#pragma unroll
        for (int i = 0; i < 4; i++)
#pragma unroll
            for (int j = 0; j < 4; j++)
                acc[i][j] = __builtin_amdgcn_mfma_f32_16x16x32_bf16(af[i], bf[j], acc[i][j], 0, 0, 0);
    }

    const int which = n0 >> 10;                 // 0=q 1=k 2=v
    const int h = ((n0 & 1023) >> 6) + wc;      // head
    if (which < 2) {
        u16* dst = which ? Kh : Qh;
        const float qsc = which ? 1.0f : 0.18033688011f;  // fold log2(e)/8 into Q
#pragma unroll
        for (int i = 0; i < 4; i++) {
#pragma unroll
            for (int r = 0; r < 4; r++) {
                const int row = m0 + wr * 64 + i * 16 + lg * 4 + r;
                const int b = row >> 11, t = row & 2047;
                const size_t rb = ((size_t)(b * 16 + h) * 2048 + t) * 64;
#pragma unroll
                for (int j = 0; j < 4; j++) {
                    float v = (acc[i][j][r] + b2f(bias[n0 + wc * 64 + j * 16 + lm])) * qsc;
                    dst[rb + j * 16 + lm] = f2b(v);
                }
            }
        }
    } else {
#pragma unroll
        for (int i = 0; i < 4; i++) {
            const int t0 = m0 + wr * 64 + i * 16 + lg * 4;
            const int b = t0 >> 11, tt = t0 & 2047;
            const int w = tt & 31;
            const int pos = (tt & ~31) + ((w & 15) >> 2) * 8 + ((w >> 4) & 1) * 4;
#pragma unroll
            for (int j = 0; j < 4; j++) {
                const int d = j * 16 + lm;
                const float bv_ = b2f(bias[n0 + wc * 64 + j * 16 + lm]);
                u16 pk[4];
#pragma unroll
                for (int r = 0; r < 4; r++) pk[r] = f2b(acc[i][j][r] + bv_);
                *(v4s*)&Vth[((size_t)(b * 16 + h) * 64 + d) * 2048 + pos] = *(const v4s*)pk;
            }
        }
    }
}

// ---------------- flash attention v6: no online-max, register-prefetch pipeline ----------------
__global__ __launch_bounds__(256, 4) void attn6_k(const u16* __restrict__ Qh,
                                                  const u16* __restrict__ Kh,
                                                  const u16* __restrict__ Vth,
                                                  u16* __restrict__ out) {
    const int tid = threadIdx.x;
    const int wid = tid >> 6, lane = tid & 63;
    const int lg = lane >> 4, lm = lane & 15;
    const int i = blockIdx.x;
    const int q = i >> 8, s = i & 255;
    const int bh = s & 31;
    const int g8 = s >> 5;
    const int g = (q == 0) ? g8 : (q == 1) ? (15 - g8) : (q == 2) ? (16 + g8) : (31 - g8);
    const int q0 = g * 64 + wid * 16;
    const int qrow_l = q0 + lm;
    const size_t qkb = (size_t)bh * 2048;
    const v4f vzero = {0.f, 0.f, 0.f, 0.f};

    v8s aq[2];
    {
        const u16* qp = Qh + (qkb + q0 + lm) * 64 + lg * 8;
        aq[0] = *(const v8s*)qp;
        aq[1] = *(const v8s*)(qp + 32);
    }
    float l_run = 0.f;
    v4f o[4];
#pragma unroll
    for (int dt = 0; dt < 4; dt++) o[dt] = vzero;

    const u16* kbase = Kh + (qkb + lm) * 64 + lg * 8;
    const u16* vbase = Vth + ((size_t)bh * 64 + lm) * 2048 + lg * 8;
    const int nchunks = g + 1;

    v8s kf[8], vf[8];
#pragma unroll
    for (int kt = 0; kt < 4; kt++) {
        kf[kt * 2]     = *(const v8s*)(kbase + kt * 1024);
        kf[kt * 2 + 1] = *(const v8s*)(kbase + kt * 1024 + 32);
    }
#pragma unroll
    for (int dt = 0; dt < 4; dt++) {
        vf[dt * 2]     = *(const v8s*)(vbase + dt * 32768);
        vf[dt * 2 + 1] = *(const v8s*)(vbase + dt * 32768 + 32);
    }

    for (int ci = 0; ci < nchunks; ++ci) {
        const int k0 = ci << 6;
        v4f sacc[4];
#pragma unroll
        for (int kt = 0; kt < 4; kt++) {
            sacc[kt] = __builtin_amdgcn_mfma_f32_16x16x32_bf16(kf[kt * 2], aq[0], vzero, 0, 0, 0);
            sacc[kt] = __builtin_amdgcn_mfma_f32_16x16x32_bf16(kf[kt * 2 + 1], aq[1], sacc[kt], 0, 0, 0);
        }
        const int cn = (ci + 1 < nchunks) ? (ci + 1) : ci;
        const u16* kb2 = kbase + cn * 4096;
#pragma unroll
        for (int kt = 0; kt < 4; kt++) {
            kf[kt * 2]     = *(const v8s*)(kb2 + kt * 1024);
            kf[kt * 2 + 1] = *(const v8s*)(kb2 + kt * 1024 + 32);
        }
        const bool dm = (ci == nchunks - 1);
        float p[16];
#pragma unroll
        for (int kt = 0; kt < 4; kt++)
#pragma unroll
            for (int r = 0; r < 4; r++) {
                float v = sacc[kt][r];
                v = (dm && (k0 + kt * 16 + lg * 4 + r > qrow_l)) ? -200.f : v;
                p[kt * 4 + r] = exp2f(v);
            }
        float ls = 0.f;
#pragma unroll
        for (int e = 0; e < 16; e++) ls += p[e];
        l_run += ls;
        u32 pk[8];
#pragma unroll
        for (int j = 0; j < 8; j++) {
            u32 lo = __float_as_uint(p[j * 2]) + 0x8000u;
            u32 hi = __float_as_uint(p[j * 2 + 1]) + 0x8000u;
            pk[j] = __builtin_amdgcn_perm(hi, lo, 0x07060302u);
        }
        v8s B0, B1;
        ((u32*)&B0)[0] = pk[0]; ((u32*)&B0)[1] = pk[1];
        ((u32*)&B0)[2] = pk[2]; ((u32*)&B0)[3] = pk[3];
        ((u32*)&B1)[0] = pk[4]; ((u32*)&B1)[1] = pk[5];
        ((u32*)&B1)[2] = pk[6]; ((u32*)&B1)[3] = pk[7];
#pragma unroll
        for (int dt = 0; dt < 4; dt++) {
            o[dt] = __builtin_amdgcn_mfma_f32_16x16x32_bf16(vf[dt * 2], B0, o[dt], 0, 0, 0);
            o[dt] = __builtin_amdgcn_mfma_f32_16x16x32_bf16(vf[dt * 2 + 1], B1, o[dt], 0, 0, 0);
        }
        const u16* vb2 = vbase + cn * 64;
#pragma unroll
        for (int dt = 0; dt < 4; dt++) {
            vf[dt * 2]     = *(const v8s*)(vb2 + dt * 32768);
            vf[dt * 2 + 1] = *(const v8s*)(vb2 + dt * 32768 + 32);
        }
    }
    l_run += __shfl_xor(l_run, 16, 64);
    l_run += __shfl_xor(l_run, 32, 64);
    const int b = bh >> 4, h = bh & 15;
    const float inv = 1.0f / l_run;
    const size_t rowb = ((size_t)b * 2048 + q0 + lm) * 1024 + h * 64;
#pragma unroll
    for (int dt = 0; dt < 4; dt++) {
        u16 pk2[4];
#pragma unroll
        for (int r = 0; r < 4; r++) pk2[r] = f2b(o[dt][r] * inv);
        *(v4s*)&out[rowb + dt * 16 + lg * 4] = *(const v4s*)pk2;
    }
}

extern "C" void kernel_launch(void* const* d_in, const int* in_sizes, int n_in,
                              void* d_out, int out_size, void* d_ws, size_t ws_size,
                              hipStream_t stream) {
    const void* x      = d_in[0];
    const void* ln1_g  = d_in[1];
    const void* ln1_b  = d_in[2];
    const void* w_attn = d_in[3];
    const void* b_attn = d_in[4];
    const void* w_proj = d_in[5];
    const void* b_proj = d_in[6];
    const void* ln2_g  = d_in[7];
    const void* ln2_b  = d_in[8];
    const void* w_fc   = d_in[9];
    const void* b_fc   = d_in[10];
    const void* w_fc2  = d_in[11];
    const void* b_fc2  = d_in[12];

    u16* ws = (u16*)d_ws;
    const size_t Mi = 1u << 20;
    u16* xb       = ws;                 // [0,4Mi)
    u16* ln_buf   = ws + 4 * Mi;        // [4,8)
    u16* h_buf    = ws + 8 * Mi;        // [8,12)
    u16* wT_attn  = ws + 12 * Mi;       // [12,15)
    u16* wT_proj  = ws + 15 * Mi;       // [15,16)
    u16* wT_fc    = ws + 16 * Mi;       // [16,20)
    u16* wT_fc2   = ws + 20 * Mi;       // [20,24)
    u16* bb       = ws + 24 * Mi;
    u16* bb_attn = bb, *bb_proj = bb + 4096, *bb_fc = bb + 8192, *bb_fc2 = bb + 12288;
    u16* gsmall   = bb + 16384;
    u16* g_ln1g = gsmall, *g_ln1b = gsmall + 1024, *g_ln2g = gsmall + 2048, *g_ln2b = gsmall + 3072;
    int* flag     = (int*)(bb + 24576);
    u16* Qh       = ws + 25 * Mi;       // [25,29) head-major Q (pre-scaled)
    u16* Kh       = ws + 29 * Mi;       // [29,33)
    u16* Vth      = ws + 33 * Mi;       // [33,37) V^T permuted [bh][d][pos(t)]
    u16* attn_buf = ws + 37 * Mi;       // [37,41)
    u16* fc_buf   = ws + 25 * Mi;       // [25,41) overlays dead Qh/Kh/Vth/attn_buf
    // total 41 Mi u16 = 82 MiB

    detect_k<<<1, 256, 0, stream>>>(x, flag);

    cvt_k<<<4096, 256, 0, stream>>>(x, xb, 4 * Mi, flag);
    P8 smalls;
    smalls.p[0] = b_attn; smalls.p[1] = b_proj; smalls.p[2] = b_fc; smalls.p[3] = b_fc2;
    smalls.p[4] = ln1_g;  smalls.p[5] = ln1_b;  smalls.p[6] = ln2_g; smalls.p[7] = ln2_b;
    cvt_small_k<<<52, 256, 0, stream>>>(smalls, bb, flag);

    dim3 tb(32, 8);
    transpose_k<<<dim3(96, 32), tb, 0, stream>>>(w_attn, wT_attn, 1024, 3072, flag);
    transpose_k<<<dim3(32, 32), tb, 0, stream>>>(w_proj, wT_proj, 1024, 1024, flag);
    transpose_k<<<dim3(128, 32), tb, 0, stream>>>(w_fc, wT_fc, 1024, 4096, flag);
    transpose_k<<<dim3(32, 128), tb, 0, stream>>>(w_fc2, wT_fc2, 4096, 1024, flag);

    layernorm_k<<<1024, 256, 0, stream>>>(xb, g_ln1g, g_ln1b, ln_buf);
    gemm_qkv_k<<<dim3(24, 32), 256, 0, stream>>>(ln_buf, wT_attn, bb_attn, Qh, Kh, Vth);
    attn6_k<<<1024, 256, 0, stream>>>(Qh, Kh, Vth, attn_buf);
    gemm_bt_k<<<dim3(8, 32), 256, 0, stream>>>(attn_buf, wT_proj, bb_proj, xb, h_buf,
                                               4096, 1024, 1024, 0, nullptr);
    layernorm_k<<<1024, 256, 0, stream>>>(h_buf, g_ln2g, g_ln2b, ln_buf);
    gemm_bt_k<<<dim3(32, 32), 256, 0, stream>>>(ln_buf, wT_fc, bb_fc, nullptr, fc_buf,
                                                4096, 4096, 1024, 1, nullptr);
    gemm_bt_k<<<dim3(8, 32), 256, 0, stream>>>(fc_buf, wT_fc2, bb_fc2, h_buf, d_out,
                                               4096, 1024, 4096, 0, flag);
}